// Round 11
// baseline (114.927 us; speedup 1.0000x reference)
//
#include <hip/hip_runtime.h>

typedef _Float16 f16;
typedef _Float16 f16x8 __attribute__((ext_vector_type(8)));
typedef float f32x4 __attribute__((ext_vector_type(4)));

// ---------------- d_ws layout ----------------
// [0, 262144) : f16 weight images, per-lane MFMA A-fragment order.
//   elem (T,ks,lane,j) at imgbase + ((T*nks + ks)*64 + lane)*16 + j*2
//   holds W[k_logical][ch = T*16 + (lane&15)] where
//     k_raw = ks*32 + (lane>>4)*8 + j
//     k_logical = k_raw                      for L1 (input from L0, raw order)
//     k_logical = klog(k_raw)                for L2..L7, C0, C1, C2 (input from
//                 an MFMA C chained in-register; klog compensates the C-row
//                 4-grouping vs B-frag 8-grouping):
//     klog(q) = 32*(q>>5) + 16*((q>>2)&1) + 4*((q>>3)&3) + (q&3)
//   L1..L7 (128x128, nks=4, 8 T): i*32768, i=0..6  (L5 uses dW5 rows 67+k)
//   C0h    (128x64,  nks=4, 4 T): 229376 | C1 (64x64, nks=2): 245760
//   C2     (64x64,   nks=2, 4 T): 253952
// [262144, +10240) : fp32 params block:
//   0 b0f[128] | 128 W0p[3][128] | 512 b5f[128] | 640 W5p[3][128]
//   1024 db1 1152 db2 1280 db3 1408 db4 1536 db6 1664 db7 (x128)
//   1792 cb0[64] | 1856 cWv[3][64] | 2048 cb1[64] | 2112 cb2[64]
//   2176 sW[128] | 2304 sb | 2308 rWT[3][64] | 2500 rb[3]
#define WS_PARAMS 262144

struct Ptrs { const float* p[29]; };

__device__ __forceinline__ int klogf(int q) {
  return ((q >> 5) << 5) | (((q >> 2) & 1) << 4) | (((q >> 3) & 3) << 2) | (q & 3);
}

// ---------------------------------------------------------------------------
// Prepass
// ---------------------------------------------------------------------------
__global__ void nerf_prep(Ptrs ptrs, char* __restrict__ ws) {
  const int t = threadIdx.x;
  if (blockIdx.x == 0) {
    float* P = (float*)(ws + WS_PARAMS);
    const float* cond = ptrs.p[1];
    const float* dW0 = ptrs.p[3];  const float* db0 = ptrs.p[4];
    const float* dW5 = ptrs.p[13]; const float* db5 = ptrs.p[14];
    if (t < 128) {
      float a0 = db0[t], a5 = db5[t];
      for (int k = 0; k < 64; ++k) {
        const float c = cond[k];
        a0 += c * dW0[(3 + k) * 128 + t];
        a5 += c * dW5[(3 + k) * 128 + t];
      }
      P[t] = a0;          // b0f
      P[512 + t] = a5;    // b5f
      for (int k = 0; k < 3; ++k) {
        P[128 + k * 128 + t] = dW0[k * 128 + t];   // W0p
        P[640 + k * 128 + t] = dW5[k * 128 + t];   // W5p
      }
      P[1024 + t] = ptrs.p[6][t];    // db1
      P[1152 + t] = ptrs.p[8][t];    // db2
      P[1280 + t] = ptrs.p[10][t];   // db3
      P[1408 + t] = ptrs.p[12][t];   // db4
      P[1536 + t] = ptrs.p[16][t];   // db6
      P[1664 + t] = ptrs.p[18][t];   // db7
      P[2176 + t] = ptrs.p[19][t];   // sW
    }
    if (t < 64) {
      P[1792 + t] = ptrs.p[22][t];   // cb0
      for (int k = 0; k < 3; ++k)    // cWv = cW0 rows 128..130
        P[1856 + k * 64 + t] = ptrs.p[21][(128 + k) * 64 + t];
      P[2048 + t] = ptrs.p[24][t];   // cb1
      P[2112 + t] = ptrs.p[26][t];   // cb2
      for (int c = 0; c < 3; ++c)    // rWT[3][64]
        P[2308 + c * 64 + t] = ptrs.p[27][t * 3 + c];
    }
    if (t == 0) {
      P[2304] = ptrs.p[20][0];                 // sb
      P[2500] = ptrs.p[28][0];
      P[2501] = ptrs.p[28][1];
      P[2502] = ptrs.p[28][2];                 // rb
    }
    // zero params gaps so staging never copies poison (slots unread anyway)
    if (t < 3)  P[2305 + t] = 0.f;
    if (t < 57) P[2503 + t] = 0.f;
    return;
  }
  // 131072 f16 weight-fragment elements across blocks 1..512
  const int e = (blockIdx.x - 1) * 256 + t;
  float v; int dst;
  if (e < 114688) {                       // L1..L7
    const int img = e >> 14, o = e & 16383;
    const int j = o & 7, lane = (o >> 3) & 63, ks = (o >> 9) & 3, T = o >> 11;
    const int kraw = ks * 32 + ((lane >> 4) << 3) + j;
    const int k = (img == 0) ? kraw : klogf(kraw);
    const int ch = T * 16 + (lane & 15);
    v = ptrs.p[5 + 2 * img][(k + (img == 4 ? 67 : 0)) * 128 + ch];
    dst = img * 32768 + (((T * 4 + ks) * 64 + lane) << 4) + (j << 1);
  } else if (e < 122880) {                // C0h (input from L7: shuffled)
    const int o = e - 114688;
    const int j = o & 7, lane = (o >> 3) & 63, ks = (o >> 9) & 3, T = o >> 11;
    const int k = klogf(ks * 32 + ((lane >> 4) << 3) + j);
    const int ch = T * 16 + (lane & 15);
    v = ptrs.p[21][k * 64 + ch];
    dst = 229376 + (((T * 4 + ks) * 64 + lane) << 4) + (j << 1);
  } else if (e < 126976) {                // C1 (input from C0: shuffled, 64)
    const int o = e - 122880;
    const int j = o & 7, lane = (o >> 3) & 63, ks = (o >> 9) & 1, T = o >> 10;
    const int k = klogf(ks * 32 + ((lane >> 4) << 3) + j);
    const int ch = T * 16 + (lane & 15);
    v = ptrs.p[23][k * 64 + ch];
    dst = 245760 + (((T * 2 + ks) * 64 + lane) << 4) + (j << 1);
  } else {                                // C2 (input from C1: shuffled, 64)
    const int o = e - 126976;
    const int j = o & 7, lane = (o >> 3) & 63, ks = (o >> 9) & 1, T = o >> 10;
    const int k = klogf(ks * 32 + ((lane >> 4) << 3) + j);
    const int ch = T * 16 + (lane & 15);
    v = ptrs.p[25][k * 64 + ch];
    dst = 253952 + (((T * 2 + ks) * 64 + lane) << 4) + (j << 1);
  }
  *(f16*)(ws + dst) = (f16)v;
}

// ---------------------------------------------------------------------------
// Barrier-free layer: A per-(ct,ks) from global fragment image; B in-register
// (own-lane, thanks to the klog weight permutation); acc[2][NCT] per wave.
// INIT: 0 bias only; 1 bias + pos*W5p; 2 bias + view*cWv
// ---------------------------------------------------------------------------
template<int NCT, int NKS, int INIT>
__device__ __forceinline__ void layerR(const f16x8 B[2][4], f32x4 acc[2][8],
                                       const char* __restrict__ img,
                                       const float* __restrict__ P,
                                       const float px[2][3],
                                       const float* __restrict__ vw2,
                                       int biasOff, int lane, int kg, int wbase) {
#pragma unroll
  for (int ct = 0; ct < NCT; ++ct) {
    const int ochB = ct * 16 + kg * 4;
    const f32x4 bq = *(const f32x4*)(P + biasOff + ochB);
    f32x4 e0, e1, e2;
    if (INIT == 1) {
      e0 = *(const f32x4*)(P + 640 + ochB);
      e1 = *(const f32x4*)(P + 768 + ochB);
      e2 = *(const f32x4*)(P + 896 + ochB);
    } else if (INIT == 2) {
      e0 = *(const f32x4*)(P + 1856 + ochB);
      e1 = *(const f32x4*)(P + 1920 + ochB);
      e2 = *(const f32x4*)(P + 1984 + ochB);
    }
#pragma unroll
    for (int ptc = 0; ptc < 2; ++ptc) {
      f32x4 v = bq;
      if (INIT == 1)
        v += px[ptc][0] * e0 + px[ptc][1] * e1 + px[ptc][2] * e2;
      if (INIT == 2) {
        const int ray = (wbase + ptc * 16) >> 7;   // wave-uniform
        v += vw2[ray * 3] * e0 + vw2[ray * 3 + 1] * e1 + vw2[ray * 3 + 2] * e2;
      }
      acc[ptc][ct] = v;
    }
  }
  __builtin_amdgcn_s_setprio(1);
#pragma unroll
  for (int ct = 0; ct < NCT; ++ct) {
    f16x8 A[NKS];
#pragma unroll
    for (int ks = 0; ks < NKS; ++ks)
      A[ks] = *(const f16x8*)(img + (((ct * NKS + ks) * 64 + lane) << 4));
#pragma unroll
    for (int ks = 0; ks < NKS; ++ks)
#pragma unroll
      for (int ptc = 0; ptc < 2; ++ptc)
        acc[ptc][ct] = __builtin_amdgcn_mfma_f32_16x16x32_f16(A[ks], B[ptc][ks],
                                                              acc[ptc][ct], 0, 0, 0);
  }
  __builtin_amdgcn_s_setprio(0);
}

// relu + f16-convert acc -> next layer's B (own-lane identity; see klog note)
template<int NCT>
__device__ __forceinline__ void toB(const f32x4 acc[2][8], f16x8 B[2][4]) {
#pragma unroll
  for (int ptc = 0; ptc < 2; ++ptc)
#pragma unroll
    for (int ks = 0; ks < NCT / 2; ++ks) {
      f16x8 hb;
#pragma unroll
      for (int r = 0; r < 4; ++r) {
        hb[r]     = (f16)fmaxf(acc[ptc][2 * ks][r], 0.f);
        hb[4 + r] = (f16)fmaxf(acc[ptc][2 * ks + 1][r], 0.f);
      }
      B[ptc][ks] = hb;
    }
}

// ---------------------------------------------------------------------------
// Main: blessed config — 512 threads, grid 1024, __launch_bounds__(512,2).
// 256 pts/block, 8 waves x 32 pts, full 128-och per wave, zero act-LDS,
// one barrier total (initial staging).
// ---------------------------------------------------------------------------
__global__ __launch_bounds__(512, 2) void nerf_main(
    const float* __restrict__ pos, const float* __restrict__ view,
    const char* __restrict__ ws, float* __restrict__ out) {
  __shared__ __align__(16) float Lp[2560 + 768 + 8];  // params | pos | view
  const int t = threadIdx.x, lane = t & 63, w = t >> 6;
  const int c = lane & 15, kg = lane >> 4;
  const int base = blockIdx.x * 256;
  const int wbase = w * 32;
  const float* P = Lp;
  float* Lpos = Lp + 2560;
  float* Lvw = Lp + 3328;

  for (int i = t; i < 2560; i += 512) Lp[i] = ((const float*)(ws + WS_PARAMS))[i];
  for (int i = t; i < 768; i += 512) Lpos[i] = pos[base * 3 + i];
  if (t < 6) Lvw[t] = view[(base >> 7) * 3 + t];
  __syncthreads();

  // per-lane pos for its two point-tiles
  float px[2][3];
#pragma unroll
  for (int ptc = 0; ptc < 2; ++ptc) {
    const int lp = wbase + ptc * 16 + c;
#pragma unroll
    for (int d = 0; d < 3; ++d) px[ptc][d] = Lpos[lp * 3 + d];
  }

  // ---- L0: emit h0 directly as L1's B-frags (raw k-order) ----
  f16x8 B[2][4];
#pragma unroll
  for (int ptc = 0; ptc < 2; ++ptc)
#pragma unroll
    for (int ks = 0; ks < 4; ++ks) {
      f16x8 hb;
#pragma unroll
      for (int j = 0; j < 8; ++j) {
        const int ch = ks * 32 + kg * 8 + j;
        const float v = P[ch] + px[ptc][0] * P[128 + ch] + px[ptc][1] * P[256 + ch]
                      + px[ptc][2] * P[384 + ch];
        hb[j] = (f16)fmaxf(v, 0.f);
      }
      B[ptc][ks] = hb;
    }

  f32x4 acc[2][8];
  layerR<8,4,0>(B, acc, ws +      0, P, px, Lvw, 1024, lane, kg, wbase); toB<8>(acc, B); // L1
  layerR<8,4,0>(B, acc, ws +  32768, P, px, Lvw, 1152, lane, kg, wbase); toB<8>(acc, B); // L2
  layerR<8,4,0>(B, acc, ws +  65536, P, px, Lvw, 1280, lane, kg, wbase); toB<8>(acc, B); // L3
  layerR<8,4,0>(B, acc, ws +  98304, P, px, Lvw, 1408, lane, kg, wbase); toB<8>(acc, B); // L4
  layerR<8,4,1>(B, acc, ws + 131072, P, px, Lvw,  512, lane, kg, wbase); toB<8>(acc, B); // L5 skip
  layerR<8,4,0>(B, acc, ws + 163840, P, px, Lvw, 1536, lane, kg, wbase); toB<8>(acc, B); // L6
  layerR<8,4,0>(B, acc, ws + 196608, P, px, Lvw, 1664, lane, kg, wbase);                 // L7

  // ---- sigma from L7 acc (f32, relu'd), in-register reduce ----
  float sig[2];
#pragma unroll
  for (int ptc = 0; ptc < 2; ++ptc) {
    float s = 0.f;
#pragma unroll
    for (int ct = 0; ct < 8; ++ct) {
      const f32x4 wq = *(const f32x4*)(P + 2176 + ct * 16 + kg * 4);
      const f32x4 a = acc[ptc][ct];
#pragma unroll
      for (int r = 0; r < 4; ++r) s += fmaxf(a[r], 0.f) * wq[r];
    }
    s += __shfl_xor(s, 16);
    s += __shfl_xor(s, 32);
    sig[ptc] = s + P[2304];
  }
  toB<8>(acc, B);                                                                        // h7 -> C0 B

  layerR<4,4,2>(B, acc, ws + 229376, P, px, Lvw, 1792, lane, kg, wbase); toB<4>(acc, B); // C0
  layerR<4,2,0>(B, acc, ws + 245760, P, px, Lvw, 2048, lane, kg, wbase); toB<4>(acc, B); // C1
  layerR<4,2,0>(B, acc, ws + 253952, P, px, Lvw, 2112, lane, kg, wbase);                 // C2

  // ---- rgb from C2 acc, in-register reduce; lanes kg==0 store float4 ----
#pragma unroll
  for (int ptc = 0; ptc < 2; ++ptc) {
    float a0 = 0.f, a1 = 0.f, a2 = 0.f;
#pragma unroll
    for (int ct = 0; ct < 4; ++ct) {
      const int ochB = ct * 16 + kg * 4;
      const f32x4 r0 = *(const f32x4*)(P + 2308 + ochB);
      const f32x4 r1 = *(const f32x4*)(P + 2372 + ochB);
      const f32x4 r2 = *(const f32x4*)(P + 2436 + ochB);
      const f32x4 a = acc[ptc][ct];
#pragma unroll
      for (int r = 0; r < 4; ++r) {
        const float h = fmaxf(a[r], 0.f);
        a0 += h * r0[r]; a1 += h * r1[r]; a2 += h * r2[r];
      }
    }
    a0 += __shfl_xor(a0, 16); a0 += __shfl_xor(a0, 32);
    a1 += __shfl_xor(a1, 16); a1 += __shfl_xor(a1, 32);
    a2 += __shfl_xor(a2, 16); a2 += __shfl_xor(a2, 32);
    if (kg == 0) {
      float4 o;
      o.x = a0 + P[2500]; o.y = a1 + P[2501]; o.z = a2 + P[2502]; o.w = sig[ptc];
      *(float4*)(out + (base + wbase + ptc * 16 + c) * 4) = o;
    }
  }
}

extern "C" void kernel_launch(void* const* d_in, const int* in_sizes, int n_in,
                              void* d_out, int out_size, void* d_ws, size_t ws_size,
                              hipStream_t stream) {
  Ptrs ptrs;
  for (int i = 0; i < 29; ++i) ptrs.p[i] = (const float*)d_in[i];
  char* ws = (char*)d_ws;
  nerf_prep<<<513, 256, 0, stream>>>(ptrs, ws);
  nerf_main<<<1024, 512, 0, stream>>>((const float*)d_in[0], (const float*)d_in[2],
                                      ws, (float*)d_out);
}

// Round 12
// 103.683 us; speedup vs baseline: 1.1084x; 1.1084x over previous
//
#include <hip/hip_runtime.h>

typedef _Float16 f16;
typedef _Float16 f16x8 __attribute__((ext_vector_type(8)));
typedef float f32x4 __attribute__((ext_vector_type(4)));

// ---------------- d_ws layout ----------------
// [0, 262144) : f16 weight images, per-lane MFMA A-fragment order.
//   elem (T,ks,lane,j) at imgbase + ((T*nks + ks)*64 + lane)*16 + j*2
//   holds W[k_logical][ch = T*16 + (lane&15)] where
//     k_raw = ks*32 + (lane>>4)*8 + j
//     k_logical = k_raw                      for L1 (input from L0, raw order)
//     k_logical = klog(k_raw)                for L2..L7, C0, C1, C2 (input from
//                 an MFMA C chained in-register; klog compensates the C-row
//                 4-grouping vs B-frag 8-grouping):
//     klog(q) = 32*(q>>5) + 16*((q>>2)&1) + 4*((q>>3)&3) + (q&3)
//   L1..L7 (128x128, nks=4, 8 T): i*32768, i=0..6  (L5 uses dW5 rows 67+k)
//   C0h    (128x64,  nks=4, 4 T): 229376 | C1 (64x64, nks=2): 245760
//   C2     (64x64,   nks=2, 4 T): 253952
// [262144, +10240) : fp32 params block:
//   0 b0f[128] | 128 W0p[3][128] | 512 b5f[128] | 640 W5p[3][128]
//   1024 db1 1152 db2 1280 db3 1408 db4 1536 db6 1664 db7 (x128)
//   1792 cb0[64] | 1856 cWv[3][64] | 2048 cb1[64] | 2112 cb2[64]
//   2176 sW[128] | 2304 sb | 2308 rWT[3][64] | 2500 rb[3]
#define WS_PARAMS 262144

struct Ptrs { const float* p[29]; };

__device__ __forceinline__ int klogf(int q) {
  return ((q >> 5) << 5) | (((q >> 2) & 1) << 4) | (((q >> 3) & 3) << 2) | (q & 3);
}

// ---------------------------------------------------------------------------
// Prepass (verbatim from passing R11)
// ---------------------------------------------------------------------------
__global__ void nerf_prep(Ptrs ptrs, char* __restrict__ ws) {
  const int t = threadIdx.x;
  if (blockIdx.x == 0) {
    float* P = (float*)(ws + WS_PARAMS);
    const float* cond = ptrs.p[1];
    const float* dW0 = ptrs.p[3];  const float* db0 = ptrs.p[4];
    const float* dW5 = ptrs.p[13]; const float* db5 = ptrs.p[14];
    if (t < 128) {
      float a0 = db0[t], a5 = db5[t];
      for (int k = 0; k < 64; ++k) {
        const float c = cond[k];
        a0 += c * dW0[(3 + k) * 128 + t];
        a5 += c * dW5[(3 + k) * 128 + t];
      }
      P[t] = a0;          // b0f
      P[512 + t] = a5;    // b5f
      for (int k = 0; k < 3; ++k) {
        P[128 + k * 128 + t] = dW0[k * 128 + t];   // W0p
        P[640 + k * 128 + t] = dW5[k * 128 + t];   // W5p
      }
      P[1024 + t] = ptrs.p[6][t];    // db1
      P[1152 + t] = ptrs.p[8][t];    // db2
      P[1280 + t] = ptrs.p[10][t];   // db3
      P[1408 + t] = ptrs.p[12][t];   // db4
      P[1536 + t] = ptrs.p[16][t];   // db6
      P[1664 + t] = ptrs.p[18][t];   // db7
      P[2176 + t] = ptrs.p[19][t];   // sW
    }
    if (t < 64) {
      P[1792 + t] = ptrs.p[22][t];   // cb0
      for (int k = 0; k < 3; ++k)    // cWv = cW0 rows 128..130
        P[1856 + k * 64 + t] = ptrs.p[21][(128 + k) * 64 + t];
      P[2048 + t] = ptrs.p[24][t];   // cb1
      P[2112 + t] = ptrs.p[26][t];   // cb2
      for (int c = 0; c < 3; ++c)    // rWT[3][64]
        P[2308 + c * 64 + t] = ptrs.p[27][t * 3 + c];
    }
    if (t == 0) {
      P[2304] = ptrs.p[20][0];                 // sb
      P[2500] = ptrs.p[28][0];
      P[2501] = ptrs.p[28][1];
      P[2502] = ptrs.p[28][2];                 // rb
    }
    // zero params gaps so staging never copies poison (slots unread anyway)
    if (t < 3)  P[2305 + t] = 0.f;
    if (t < 57) P[2503 + t] = 0.f;
    return;
  }
  // 131072 f16 weight-fragment elements across blocks 1..512
  const int e = (blockIdx.x - 1) * 256 + t;
  float v; int dst;
  if (e < 114688) {                       // L1..L7
    const int img = e >> 14, o = e & 16383;
    const int j = o & 7, lane = (o >> 3) & 63, ks = (o >> 9) & 3, T = o >> 11;
    const int kraw = ks * 32 + ((lane >> 4) << 3) + j;
    const int k = (img == 0) ? kraw : klogf(kraw);
    const int ch = T * 16 + (lane & 15);
    v = ptrs.p[5 + 2 * img][(k + (img == 4 ? 67 : 0)) * 128 + ch];
    dst = img * 32768 + (((T * 4 + ks) * 64 + lane) << 4) + (j << 1);
  } else if (e < 122880) {                // C0h (input from L7: shuffled)
    const int o = e - 114688;
    const int j = o & 7, lane = (o >> 3) & 63, ks = (o >> 9) & 3, T = o >> 11;
    const int k = klogf(ks * 32 + ((lane >> 4) << 3) + j);
    const int ch = T * 16 + (lane & 15);
    v = ptrs.p[21][k * 64 + ch];
    dst = 229376 + (((T * 4 + ks) * 64 + lane) << 4) + (j << 1);
  } else if (e < 126976) {                // C1 (input from C0: shuffled, 64)
    const int o = e - 122880;
    const int j = o & 7, lane = (o >> 3) & 63, ks = (o >> 9) & 1, T = o >> 10;
    const int k = klogf(ks * 32 + ((lane >> 4) << 3) + j);
    const int ch = T * 16 + (lane & 15);
    v = ptrs.p[23][k * 64 + ch];
    dst = 245760 + (((T * 2 + ks) * 64 + lane) << 4) + (j << 1);
  } else {                                // C2 (input from C1: shuffled, 64)
    const int o = e - 126976;
    const int j = o & 7, lane = (o >> 3) & 63, ks = (o >> 9) & 1, T = o >> 10;
    const int k = klogf(ks * 32 + ((lane >> 4) << 3) + j);
    const int ch = T * 16 + (lane & 15);
    v = ptrs.p[25][k * 64 + ch];
    dst = 253952 + (((T * 2 + ks) * 64 + lane) << 4) + (j << 1);
  }
  *(f16*)(ws + dst) = (f16)v;
}

// ---------------------------------------------------------------------------
// Barrier-free layer with HOISTED A-load burst: all NCT*NKS fragment loads
// issue back-to-back into a fully-unrolled register array (static indices),
// so one memory-latency window covers the whole layer; the acc-init VALU
// block and the co-resident wave's MFMAs execute under it. VGPR peak
// ~240 <= 256 (the __launch_bounds__(512,2) cap).
// INIT: 0 bias only; 1 bias + pos*W5p; 2 bias + view*cWv
// ---------------------------------------------------------------------------
template<int NCT, int NKS, int INIT>
__device__ __forceinline__ void layerR(const f16x8 B[2][4], f32x4 acc[2][8],
                                       const char* __restrict__ img,
                                       const float* __restrict__ P,
                                       const float px[2][3],
                                       const float* __restrict__ vw2,
                                       int biasOff, int lane, int kg, int wbase) {
  f16x8 A[NCT][NKS];
#pragma unroll
  for (int ct = 0; ct < NCT; ++ct)
#pragma unroll
    for (int ks = 0; ks < NKS; ++ks)
      A[ct][ks] = *(const f16x8*)(img + (((ct * NKS + ks) * 64 + lane) << 4));
  // acc init (VALU) — overlaps the in-flight A loads
#pragma unroll
  for (int ct = 0; ct < NCT; ++ct) {
    const int ochB = ct * 16 + kg * 4;
    const f32x4 bq = *(const f32x4*)(P + biasOff + ochB);
    f32x4 e0, e1, e2;
    if (INIT == 1) {
      e0 = *(const f32x4*)(P + 640 + ochB);
      e1 = *(const f32x4*)(P + 768 + ochB);
      e2 = *(const f32x4*)(P + 896 + ochB);
    } else if (INIT == 2) {
      e0 = *(const f32x4*)(P + 1856 + ochB);
      e1 = *(const f32x4*)(P + 1920 + ochB);
      e2 = *(const f32x4*)(P + 1984 + ochB);
    }
#pragma unroll
    for (int ptc = 0; ptc < 2; ++ptc) {
      f32x4 v = bq;
      if (INIT == 1)
        v += px[ptc][0] * e0 + px[ptc][1] * e1 + px[ptc][2] * e2;
      if (INIT == 2) {
        const int ray = (wbase + ptc * 16) >> 7;   // wave-uniform
        v += vw2[ray * 3] * e0 + vw2[ray * 3 + 1] * e1 + vw2[ray * 3 + 2] * e2;
      }
      acc[ptc][ct] = v;
    }
  }
  __builtin_amdgcn_s_setprio(1);
#pragma unroll
  for (int ct = 0; ct < NCT; ++ct)
#pragma unroll
    for (int ks = 0; ks < NKS; ++ks)
#pragma unroll
      for (int ptc = 0; ptc < 2; ++ptc)
        acc[ptc][ct] = __builtin_amdgcn_mfma_f32_16x16x32_f16(A[ct][ks], B[ptc][ks],
                                                              acc[ptc][ct], 0, 0, 0);
  __builtin_amdgcn_s_setprio(0);
}

// relu + f16-convert acc -> next layer's B (own-lane identity via klog)
template<int NCT>
__device__ __forceinline__ void toB(const f32x4 acc[2][8], f16x8 B[2][4]) {
#pragma unroll
  for (int ptc = 0; ptc < 2; ++ptc)
#pragma unroll
    for (int ks = 0; ks < NCT / 2; ++ks) {
      f16x8 hb;
#pragma unroll
      for (int r = 0; r < 4; ++r) {
        hb[r]     = (f16)fmaxf(acc[ptc][2 * ks][r], 0.f);
        hb[4 + r] = (f16)fmaxf(acc[ptc][2 * ks + 1][r], 0.f);
      }
      B[ptc][ks] = hb;
    }
}

// ---------------------------------------------------------------------------
// Main: blessed config — 512 threads, grid 1024, __launch_bounds__(512,2).
// 256 pts/block, 8 waves x 32 pts, full 128-och per wave, zero act-LDS,
// one barrier total. Identical to passing R11 except layerR's load hoist.
// ---------------------------------------------------------------------------
__global__ __launch_bounds__(512, 2) void nerf_main(
    const float* __restrict__ pos, const float* __restrict__ view,
    const char* __restrict__ ws, float* __restrict__ out) {
  __shared__ __align__(16) float Lp[2560 + 768 + 8];  // params | pos | view
  const int t = threadIdx.x, lane = t & 63, w = t >> 6;
  const int c = lane & 15, kg = lane >> 4;
  const int base = blockIdx.x * 256;
  const int wbase = w * 32;
  const float* P = Lp;
  float* Lpos = Lp + 2560;
  float* Lvw = Lp + 3328;

  for (int i = t; i < 2560; i += 512) Lp[i] = ((const float*)(ws + WS_PARAMS))[i];
  for (int i = t; i < 768; i += 512) Lpos[i] = pos[base * 3 + i];
  if (t < 6) Lvw[t] = view[(base >> 7) * 3 + t];
  __syncthreads();

  // per-lane pos for its two point-tiles
  float px[2][3];
#pragma unroll
  for (int ptc = 0; ptc < 2; ++ptc) {
    const int lp = wbase + ptc * 16 + c;
#pragma unroll
    for (int d = 0; d < 3; ++d) px[ptc][d] = Lpos[lp * 3 + d];
  }

  // ---- L0: emit h0 directly as L1's B-frags (raw k-order) ----
  f16x8 B[2][4];
#pragma unroll
  for (int ptc = 0; ptc < 2; ++ptc)
#pragma unroll
    for (int ks = 0; ks < 4; ++ks) {
      f16x8 hb;
#pragma unroll
      for (int j = 0; j < 8; ++j) {
        const int ch = ks * 32 + kg * 8 + j;
        const float v = P[ch] + px[ptc][0] * P[128 + ch] + px[ptc][1] * P[256 + ch]
                      + px[ptc][2] * P[384 + ch];
        hb[j] = (f16)fmaxf(v, 0.f);
      }
      B[ptc][ks] = hb;
    }

  f32x4 acc[2][8];
  layerR<8,4,0>(B, acc, ws +      0, P, px, Lvw, 1024, lane, kg, wbase); toB<8>(acc, B); // L1
  layerR<8,4,0>(B, acc, ws +  32768, P, px, Lvw, 1152, lane, kg, wbase); toB<8>(acc, B); // L2
  layerR<8,4,0>(B, acc, ws +  65536, P, px, Lvw, 1280, lane, kg, wbase); toB<8>(acc, B); // L3
  layerR<8,4,0>(B, acc, ws +  98304, P, px, Lvw, 1408, lane, kg, wbase); toB<8>(acc, B); // L4
  layerR<8,4,1>(B, acc, ws + 131072, P, px, Lvw,  512, lane, kg, wbase); toB<8>(acc, B); // L5 skip
  layerR<8,4,0>(B, acc, ws + 163840, P, px, Lvw, 1536, lane, kg, wbase); toB<8>(acc, B); // L6
  layerR<8,4,0>(B, acc, ws + 196608, P, px, Lvw, 1664, lane, kg, wbase);                 // L7

  // ---- sigma from L7 acc (f32, relu'd), in-register reduce ----
  float sig[2];
#pragma unroll
  for (int ptc = 0; ptc < 2; ++ptc) {
    float s = 0.f;
#pragma unroll
    for (int ct = 0; ct < 8; ++ct) {
      const f32x4 wq = *(const f32x4*)(P + 2176 + ct * 16 + kg * 4);
      const f32x4 a = acc[ptc][ct];
#pragma unroll
      for (int r = 0; r < 4; ++r) s += fmaxf(a[r], 0.f) * wq[r];
    }
    s += __shfl_xor(s, 16);
    s += __shfl_xor(s, 32);
    sig[ptc] = s + P[2304];
  }
  toB<8>(acc, B);                                                                        // h7 -> C0 B

  layerR<4,4,2>(B, acc, ws + 229376, P, px, Lvw, 1792, lane, kg, wbase); toB<4>(acc, B); // C0
  layerR<4,2,0>(B, acc, ws + 245760, P, px, Lvw, 2048, lane, kg, wbase); toB<4>(acc, B); // C1
  layerR<4,2,0>(B, acc, ws + 253952, P, px, Lvw, 2112, lane, kg, wbase);                 // C2

  // ---- rgb from C2 acc, in-register reduce; lanes kg==0 store float4 ----
#pragma unroll
  for (int ptc = 0; ptc < 2; ++ptc) {
    float a0 = 0.f, a1 = 0.f, a2 = 0.f;
#pragma unroll
    for (int ct = 0; ct < 4; ++ct) {
      const int ochB = ct * 16 + kg * 4;
      const f32x4 r0 = *(const f32x4*)(P + 2308 + ochB);
      const f32x4 r1 = *(const f32x4*)(P + 2372 + ochB);
      const f32x4 r2 = *(const f32x4*)(P + 2436 + ochB);
      const f32x4 a = acc[ptc][ct];
#pragma unroll
      for (int r = 0; r < 4; ++r) {
        const float h = fmaxf(a[r], 0.f);
        a0 += h * r0[r]; a1 += h * r1[r]; a2 += h * r2[r];
      }
    }
    a0 += __shfl_xor(a0, 16); a0 += __shfl_xor(a0, 32);
    a1 += __shfl_xor(a1, 16); a1 += __shfl_xor(a1, 32);
    a2 += __shfl_xor(a2, 16); a2 += __shfl_xor(a2, 32);
    if (kg == 0) {
      float4 o;
      o.x = a0 + P[2500]; o.y = a1 + P[2501]; o.z = a2 + P[2502]; o.w = sig[ptc];
      *(float4*)(out + (base + wbase + ptc * 16 + c) * 4) = o;
    }
  }
}

extern "C" void kernel_launch(void* const* d_in, const int* in_sizes, int n_in,
                              void* d_out, int out_size, void* d_ws, size_t ws_size,
                              hipStream_t stream) {
  Ptrs ptrs;
  for (int i = 0; i < 29; ++i) ptrs.p[i] = (const float*)d_in[i];
  char* ws = (char*)d_ws;
  nerf_prep<<<513, 256, 0, stream>>>(ptrs, ws);
  nerf_main<<<1024, 512, 0, stream>>>((const float*)d_in[0], (const float*)d_in[2],
                                      ws, (float*)d_out);
}

// Round 13
// 103.494 us; speedup vs baseline: 1.1105x; 1.0018x over previous
//
#include <hip/hip_runtime.h>

typedef _Float16 f16;
typedef _Float16 f16x8 __attribute__((ext_vector_type(8)));
typedef float f32x4 __attribute__((ext_vector_type(4)));

// ---------------- d_ws layout ----------------
// [0, 262144) : f16 weight images, per-lane MFMA A-fragment order.
//   elem (T,ks,lane,j) at imgbase + ((T*nks + ks)*64 + lane)*16 + j*2
//   holds W[k_logical][ch = T*16 + (lane&15)] where
//     k_raw = ks*32 + (lane>>4)*8 + j
//     k_logical = k_raw       for L1 (input from L0, raw order)
//     k_logical = klog(k_raw) for L2..L7, C0, C1, C2 (in-register chaining;
//                 klog compensates C-row 4-grouping vs B-frag 8-grouping):
//     klog(q) = 32*(q>>5) + 16*((q>>2)&1) + 4*((q>>3)&3) + (q&3)
//   L1..L7 (128x128, nks=4): i*32768, i=0..6  (L5 uses dW5 rows 67+k)
//   C0h    (128x64,  nks=4): 229376 | C1 (64x64, nks=2): 245760
//   C2     (64x64,   nks=2): 253952
// [262144, +10240) : fp32 params block:
//   0 b0f[128] | 128 W0p[3][128] | 512 b5f[128] | 640 W5p[3][128]
//   1024 db1 1152 db2 1280 db3 1408 db4 1536 db6 1664 db7 (x128)
//   1792 cb0[64] | 1856 cWv[3][64] | 2048 cb1[64] | 2112 cb2[64]
//   2176 sW[128] | 2304 sb | 2308 rWT[3][64] | 2500 rb[3]
#define WS_PARAMS 262144

struct Ptrs { const float* p[29]; };

__device__ __forceinline__ int klogf(int q) {
  return ((q >> 5) << 5) | (((q >> 2) & 1) << 4) | (((q >> 3) & 3) << 2) | (q & 3);
}

// ---------------------------------------------------------------------------
// Prepass (verbatim from passing R11/R12)
// ---------------------------------------------------------------------------
__global__ void nerf_prep(Ptrs ptrs, char* __restrict__ ws) {
  const int t = threadIdx.x;
  if (blockIdx.x == 0) {
    float* P = (float*)(ws + WS_PARAMS);
    const float* cond = ptrs.p[1];
    const float* dW0 = ptrs.p[3];  const float* db0 = ptrs.p[4];
    const float* dW5 = ptrs.p[13]; const float* db5 = ptrs.p[14];
    if (t < 128) {
      float a0 = db0[t], a5 = db5[t];
      for (int k = 0; k < 64; ++k) {
        const float c = cond[k];
        a0 += c * dW0[(3 + k) * 128 + t];
        a5 += c * dW5[(3 + k) * 128 + t];
      }
      P[t] = a0;          // b0f
      P[512 + t] = a5;    // b5f
      for (int k = 0; k < 3; ++k) {
        P[128 + k * 128 + t] = dW0[k * 128 + t];   // W0p
        P[640 + k * 128 + t] = dW5[k * 128 + t];   // W5p
      }
      P[1024 + t] = ptrs.p[6][t];    // db1
      P[1152 + t] = ptrs.p[8][t];    // db2
      P[1280 + t] = ptrs.p[10][t];   // db3
      P[1408 + t] = ptrs.p[12][t];   // db4
      P[1536 + t] = ptrs.p[16][t];   // db6
      P[1664 + t] = ptrs.p[18][t];   // db7
      P[2176 + t] = ptrs.p[19][t];   // sW
    }
    if (t < 64) {
      P[1792 + t] = ptrs.p[22][t];   // cb0
      for (int k = 0; k < 3; ++k)    // cWv = cW0 rows 128..130
        P[1856 + k * 64 + t] = ptrs.p[21][(128 + k) * 64 + t];
      P[2048 + t] = ptrs.p[24][t];   // cb1
      P[2112 + t] = ptrs.p[26][t];   // cb2
      for (int c = 0; c < 3; ++c)    // rWT[3][64]
        P[2308 + c * 64 + t] = ptrs.p[27][t * 3 + c];
    }
    if (t == 0) {
      P[2304] = ptrs.p[20][0];                 // sb
      P[2500] = ptrs.p[28][0];
      P[2501] = ptrs.p[28][1];
      P[2502] = ptrs.p[28][2];                 // rb
    }
    if (t < 3)  P[2305 + t] = 0.f;
    if (t < 57) P[2503 + t] = 0.f;
    return;
  }
  // 131072 f16 weight-fragment elements across blocks 1..512
  const int e = (blockIdx.x - 1) * 256 + t;
  float v; int dst;
  if (e < 114688) {                       // L1..L7
    const int img = e >> 14, o = e & 16383;
    const int j = o & 7, lane = (o >> 3) & 63, ks = (o >> 9) & 3, T = o >> 11;
    const int kraw = ks * 32 + ((lane >> 4) << 3) + j;
    const int k = (img == 0) ? kraw : klogf(kraw);
    const int ch = T * 16 + (lane & 15);
    v = ptrs.p[5 + 2 * img][(k + (img == 4 ? 67 : 0)) * 128 + ch];
    dst = img * 32768 + (((T * 4 + ks) * 64 + lane) << 4) + (j << 1);
  } else if (e < 122880) {                // C0h (input from L7: shuffled)
    const int o = e - 114688;
    const int j = o & 7, lane = (o >> 3) & 63, ks = (o >> 9) & 3, T = o >> 11;
    const int k = klogf(ks * 32 + ((lane >> 4) << 3) + j);
    const int ch = T * 16 + (lane & 15);
    v = ptrs.p[21][k * 64 + ch];
    dst = 229376 + (((T * 4 + ks) * 64 + lane) << 4) + (j << 1);
  } else if (e < 126976) {                // C1 (input from C0: shuffled)
    const int o = e - 122880;
    const int j = o & 7, lane = (o >> 3) & 63, ks = (o >> 9) & 1, T = o >> 10;
    const int k = klogf(ks * 32 + ((lane >> 4) << 3) + j);
    const int ch = T * 16 + (lane & 15);
    v = ptrs.p[23][k * 64 + ch];
    dst = 245760 + (((T * 2 + ks) * 64 + lane) << 4) + (j << 1);
  } else {                                // C2 (input from C1: shuffled)
    const int o = e - 126976;
    const int j = o & 7, lane = (o >> 3) & 63, ks = (o >> 9) & 1, T = o >> 10;
    const int k = klogf(ks * 32 + ((lane >> 4) << 3) + j);
    const int ch = T * 16 + (lane & 15);
    v = ptrs.p[25][k * 64 + ch];
    dst = 253952 + (((T * 2 + ks) * 64 + lane) << 4) + (j << 1);
  }
  *(f16*)(ws + dst) = (f16)v;
}

// ---------------------------------------------------------------------------
// Fragment burst-load into a named register buffer (static indices)
// ---------------------------------------------------------------------------
template<int N>
__device__ __forceinline__ void loadFrags(f16x8* A, const char* __restrict__ img,
                                          int fragBase, int lane) {
#pragma unroll
  for (int i = 0; i < N; ++i)
    A[i] = *(const f16x8*)(img + (((fragBase + i) * 64 + lane) << 4));
}

// ---------------------------------------------------------------------------
// Half-layer: acc-init + MFMAs for ct in [CTBASE, CTBASE+HCT) using a
// pre-loaded fragment buffer A[HCT*NKS]. INIT: 0 bias; 1 +pos*W5p; 2 +view*cWv
// ---------------------------------------------------------------------------
template<int HCT, int NKS, int INIT, int CTBASE>
__device__ __forceinline__ void halfL(const f16x8 B[2][4], f32x4 acc[2][8],
                                      const f16x8* A,
                                      const float* __restrict__ P,
                                      const float px[2][3],
                                      const float* __restrict__ vw2,
                                      int biasOff, int kg, int wbase) {
#pragma unroll
  for (int ct = 0; ct < HCT; ++ct) {
    const int ochB = (CTBASE + ct) * 16 + kg * 4;
    const f32x4 bq = *(const f32x4*)(P + biasOff + ochB);
    f32x4 e0, e1, e2;
    if (INIT == 1) {
      e0 = *(const f32x4*)(P + 640 + ochB);
      e1 = *(const f32x4*)(P + 768 + ochB);
      e2 = *(const f32x4*)(P + 896 + ochB);
    } else if (INIT == 2) {
      e0 = *(const f32x4*)(P + 1856 + ochB);
      e1 = *(const f32x4*)(P + 1920 + ochB);
      e2 = *(const f32x4*)(P + 1984 + ochB);
    }
#pragma unroll
    for (int ptc = 0; ptc < 2; ++ptc) {
      f32x4 v = bq;
      if (INIT == 1)
        v += px[ptc][0] * e0 + px[ptc][1] * e1 + px[ptc][2] * e2;
      if (INIT == 2) {
        const int ray = (wbase + ptc * 16) >> 7;   // wave-uniform
        v += vw2[ray * 3] * e0 + vw2[ray * 3 + 1] * e1 + vw2[ray * 3 + 2] * e2;
      }
      acc[ptc][CTBASE + ct] = v;
    }
  }
  __builtin_amdgcn_s_setprio(1);
#pragma unroll
  for (int ct = 0; ct < HCT; ++ct)
#pragma unroll
    for (int ks = 0; ks < NKS; ++ks)
#pragma unroll
      for (int ptc = 0; ptc < 2; ++ptc)
        acc[ptc][CTBASE + ct] = __builtin_amdgcn_mfma_f32_16x16x32_f16(
            A[ct * NKS + ks], B[ptc][ks], acc[ptc][CTBASE + ct], 0, 0, 0);
  __builtin_amdgcn_s_setprio(0);
}

// relu + f16-convert acc -> next layer's B (own-lane identity via klog)
template<int NCT>
__device__ __forceinline__ void toB(const f32x4 acc[2][8], f16x8 B[2][4]) {
#pragma unroll
  for (int ptc = 0; ptc < 2; ++ptc)
#pragma unroll
    for (int ks = 0; ks < NCT / 2; ++ks) {
      f16x8 hb;
#pragma unroll
      for (int r = 0; r < 4; ++r) {
        hb[r]     = (f16)fmaxf(acc[ptc][2 * ks][r], 0.f);
        hb[4 + r] = (f16)fmaxf(acc[ptc][2 * ks + 1][r], 0.f);
      }
      B[ptc][ks] = hb;
    }
}

// ---------------------------------------------------------------------------
// Main: blessed config — 512 threads, grid 1024, __launch_bounds__(512,2).
// 256 pts/block, 8 waves x 32 pts, full 128-och/wave, zero act-LDS, one
// barrier. Two-stage half-layer pipeline: load half(i+1) under MFMA half(i),
// crossing layer boundaries (Aa/Ab named buffers, ~240 VGPR).
// ---------------------------------------------------------------------------
__global__ __launch_bounds__(512, 2) void nerf_main(
    const float* __restrict__ pos, const float* __restrict__ view,
    const char* __restrict__ ws, float* __restrict__ out) {
  __shared__ __align__(16) float Lp[2560 + 768 + 8];  // params | pos | view
  const int t = threadIdx.x, lane = t & 63, w = t >> 6;
  const int c = lane & 15, kg = lane >> 4;
  const int base = blockIdx.x * 256;
  const int wbase = w * 32;
  const float* P = Lp;
  float* Lpos = Lp + 2560;
  float* Lvw = Lp + 3328;

  for (int i = t; i < 2560; i += 512) Lp[i] = ((const float*)(ws + WS_PARAMS))[i];
  for (int i = t; i < 768; i += 512) Lpos[i] = pos[base * 3 + i];
  if (t < 6) Lvw[t] = view[(base >> 7) * 3 + t];
  __syncthreads();

  f16x8 Aa[16], Ab[16];
  loadFrags<16>(Aa, ws + 0, 0, lane);        // L1 half0 — in flight during L0

  // per-lane pos for its two point-tiles
  float px[2][3];
#pragma unroll
  for (int ptc = 0; ptc < 2; ++ptc) {
    const int lp = wbase + ptc * 16 + c;
#pragma unroll
    for (int d = 0; d < 3; ++d) px[ptc][d] = Lpos[lp * 3 + d];
  }

  // ---- L0: emit h0 directly as L1's B-frags (raw k-order) ----
  f16x8 B[2][4];
#pragma unroll
  for (int ptc = 0; ptc < 2; ++ptc)
#pragma unroll
    for (int ks = 0; ks < 4; ++ks) {
      f16x8 hb;
#pragma unroll
      for (int j = 0; j < 8; ++j) {
        const int ch = ks * 32 + kg * 8 + j;
        const float v = P[ch] + px[ptc][0] * P[128 + ch] + px[ptc][1] * P[256 + ch]
                      + px[ptc][2] * P[384 + ch];
        hb[j] = (f16)fmaxf(v, 0.f);
      }
      B[ptc][ks] = hb;
    }

  f32x4 acc[2][8];

  // ---- density chain: load half(i+1) under MFMA half(i) ----
#define DLAYER(imgCur, imgNext, BIAS, INIT_)                                   \
  loadFrags<16>(Ab, imgCur, 16, lane);                                         \
  halfL<4, 4, INIT_, 0>(B, acc, Aa, P, px, Lvw, BIAS, kg, wbase);              \
  loadFrags<16>(Aa, imgNext, 0, lane);                                         \
  halfL<4, 4, INIT_, 4>(B, acc, Ab, P, px, Lvw, BIAS, kg, wbase);

  DLAYER(ws +      0, ws +  32768, 1024, 0) toB<8>(acc, B);  // L1
  DLAYER(ws +  32768, ws +  65536, 1152, 0) toB<8>(acc, B);  // L2
  DLAYER(ws +  65536, ws +  98304, 1280, 0) toB<8>(acc, B);  // L3
  DLAYER(ws +  98304, ws + 131072, 1408, 0) toB<8>(acc, B);  // L4
  DLAYER(ws + 131072, ws + 163840,  512, 1) toB<8>(acc, B);  // L5 (skip)
  DLAYER(ws + 163840, ws + 196608, 1536, 0) toB<8>(acc, B);  // L6
  DLAYER(ws + 196608, ws + 229376, 1664, 0)                  // L7 (prefetches C0)
#undef DLAYER

  // ---- sigma from L7 acc (f32, relu'd), in-register reduce ----
  float sig[2];
#pragma unroll
  for (int ptc = 0; ptc < 2; ++ptc) {
    float s = 0.f;
#pragma unroll
    for (int ct = 0; ct < 8; ++ct) {
      const f32x4 wq = *(const f32x4*)(P + 2176 + ct * 16 + kg * 4);
      const f32x4 a = acc[ptc][ct];
#pragma unroll
      for (int r = 0; r < 4; ++r) s += fmaxf(a[r], 0.f) * wq[r];
    }
    s += __shfl_xor(s, 16);
    s += __shfl_xor(s, 32);
    sig[ptc] = s + P[2304];
  }
  toB<8>(acc, B);                                            // h7 -> C0 B

  // ---- color chain (C0 frags already in Aa) ----
  loadFrags<8>(Ab, ws + 245760, 0, lane);                    // C1
  halfL<4, 4, 2, 0>(B, acc, Aa, P, px, Lvw, 1792, kg, wbase);
  toB<4>(acc, B);                                            // C0 -> B
  loadFrags<8>(Aa, ws + 253952, 0, lane);                    // C2
  halfL<4, 2, 0, 0>(B, acc, Ab, P, px, Lvw, 2048, kg, wbase);
  toB<4>(acc, B);                                            // C1 -> B
  halfL<4, 2, 0, 0>(B, acc, Aa, P, px, Lvw, 2112, kg, wbase);

  // ---- rgb from C2 acc, in-register reduce; lanes kg==0 store float4 ----
#pragma unroll
  for (int ptc = 0; ptc < 2; ++ptc) {
    float a0 = 0.f, a1 = 0.f, a2 = 0.f;
#pragma unroll
    for (int ct = 0; ct < 4; ++ct) {
      const int ochB = ct * 16 + kg * 4;
      const f32x4 r0 = *(const f32x4*)(P + 2308 + ochB);
      const f32x4 r1 = *(const f32x4*)(P + 2372 + ochB);
      const f32x4 r2 = *(const f32x4*)(P + 2436 + ochB);
      const f32x4 a = acc[ptc][ct];
#pragma unroll
      for (int r = 0; r < 4; ++r) {
        const float h = fmaxf(a[r], 0.f);
        a0 += h * r0[r]; a1 += h * r1[r]; a2 += h * r2[r];
      }
    }
    a0 += __shfl_xor(a0, 16); a0 += __shfl_xor(a0, 32);
    a1 += __shfl_xor(a1, 16); a1 += __shfl_xor(a1, 32);
    a2 += __shfl_xor(a2, 16); a2 += __shfl_xor(a2, 32);
    if (kg == 0) {
      float4 o;
      o.x = a0 + P[2500]; o.y = a1 + P[2501]; o.z = a2 + P[2502]; o.w = sig[ptc];
      *(float4*)(out + (base + wbase + ptc * 16 + c) * 4) = o;
    }
  }
}

extern "C" void kernel_launch(void* const* d_in, const int* in_sizes, int n_in,
                              void* d_out, int out_size, void* d_ws, size_t ws_size,
                              hipStream_t stream) {
  Ptrs ptrs;
  for (int i = 0; i < 29; ++i) ptrs.p[i] = (const float*)d_in[i];
  char* ws = (char*)d_ws;
  nerf_prep<<<513, 256, 0, stream>>>(ptrs, ws);
  nerf_main<<<1024, 512, 0, stream>>>((const float*)d_in[0], (const float*)d_in[2],
                                      ws, (float*)d_out);
}

// Round 14
// 82.333 us; speedup vs baseline: 1.3959x; 1.2570x over previous
//
#include <hip/hip_runtime.h>

typedef _Float16 f16;
typedef _Float16 f16x8 __attribute__((ext_vector_type(8)));
typedef float f32x4 __attribute__((ext_vector_type(4)));

// ---------------- d_ws layout ----------------
// [0, 262144) : f16 weight images, per-lane MFMA A-fragment order.
//   frag f = T*nks + ks at imgbase + (f*64 + lane)*16 + j*2, holding
//   W[k_logical][ch = T*16 + (lane&15)], k_raw = ks*32 + (lane>>4)*8 + j
//     k_logical = k_raw       for L1 (input from L0, raw order)
//     k_logical = klog(k_raw) for L2..L7, C0, C1, C2 (in-register chaining):
//     klog(q) = 32*(q>>5) + 16*((q>>2)&1) + 4*((q>>3)&3) + (q&3)
//   L1..L7 (128x128, nks=4): i*32768, i=0..6  (L5 uses dW5 rows 67+k)
//   C0h (128x64, nks=4): 229376 | C1 (64x64, nks=2): 245760 | C2: 253952
// [262144, +10240) : fp32 params block (same as R11..R13):
//   0 b0f[128] | 128 W0p[3][128] | 512 b5f[128] | 640 W5p[3][128]
//   1024 db1 1152 db2 1280 db3 1408 db4 1536 db6 1664 db7 (x128)
//   1792 cb0[64] | 1856 cWv[3][64] | 2048 cb1[64] | 2112 cb2[64]
//   2176 sW[128] | 2304 sb | 2308 rWT[3][64] | 2500 rb[3]
#define WS_PARAMS 262144

struct Ptrs { const float* p[29]; };

__device__ __forceinline__ int klogf(int q) {
  return ((q >> 5) << 5) | (((q >> 2) & 1) << 4) | (((q >> 3) & 3) << 2) | (q & 3);
}

// ---------------------------------------------------------------------------
// Prepass (verbatim from passing R11..R13)
// ---------------------------------------------------------------------------
__global__ void nerf_prep(Ptrs ptrs, char* __restrict__ ws) {
  const int t = threadIdx.x;
  if (blockIdx.x == 0) {
    float* P = (float*)(ws + WS_PARAMS);
    const float* cond = ptrs.p[1];
    const float* dW0 = ptrs.p[3];  const float* db0 = ptrs.p[4];
    const float* dW5 = ptrs.p[13]; const float* db5 = ptrs.p[14];
    if (t < 128) {
      float a0 = db0[t], a5 = db5[t];
      for (int k = 0; k < 64; ++k) {
        const float c = cond[k];
        a0 += c * dW0[(3 + k) * 128 + t];
        a5 += c * dW5[(3 + k) * 128 + t];
      }
      P[t] = a0;          // b0f
      P[512 + t] = a5;    // b5f
      for (int k = 0; k < 3; ++k) {
        P[128 + k * 128 + t] = dW0[k * 128 + t];   // W0p
        P[640 + k * 128 + t] = dW5[k * 128 + t];   // W5p
      }
      P[1024 + t] = ptrs.p[6][t];    // db1
      P[1152 + t] = ptrs.p[8][t];    // db2
      P[1280 + t] = ptrs.p[10][t];   // db3
      P[1408 + t] = ptrs.p[12][t];   // db4
      P[1536 + t] = ptrs.p[16][t];   // db6
      P[1664 + t] = ptrs.p[18][t];   // db7
      P[2176 + t] = ptrs.p[19][t];   // sW
    }
    if (t < 64) {
      P[1792 + t] = ptrs.p[22][t];   // cb0
      for (int k = 0; k < 3; ++k)    // cWv = cW0 rows 128..130
        P[1856 + k * 64 + t] = ptrs.p[21][(128 + k) * 64 + t];
      P[2048 + t] = ptrs.p[24][t];   // cb1
      P[2112 + t] = ptrs.p[26][t];   // cb2
      for (int c = 0; c < 3; ++c)    // rWT[3][64]
        P[2308 + c * 64 + t] = ptrs.p[27][t * 3 + c];
    }
    if (t == 0) {
      P[2304] = ptrs.p[20][0];                 // sb
      P[2500] = ptrs.p[28][0];
      P[2501] = ptrs.p[28][1];
      P[2502] = ptrs.p[28][2];                 // rb
    }
    if (t < 3)  P[2305 + t] = 0.f;
    if (t < 57) P[2503 + t] = 0.f;
    return;
  }
  // 131072 f16 weight-fragment elements across blocks 1..512
  const int e = (blockIdx.x - 1) * 256 + t;
  float v; int dst;
  if (e < 114688) {                       // L1..L7
    const int img = e >> 14, o = e & 16383;
    const int j = o & 7, lane = (o >> 3) & 63, ks = (o >> 9) & 3, T = o >> 11;
    const int kraw = ks * 32 + ((lane >> 4) << 3) + j;
    const int k = (img == 0) ? kraw : klogf(kraw);
    const int ch = T * 16 + (lane & 15);
    v = ptrs.p[5 + 2 * img][(k + (img == 4 ? 67 : 0)) * 128 + ch];
    dst = img * 32768 + (((T * 4 + ks) * 64 + lane) << 4) + (j << 1);
  } else if (e < 122880) {                // C0h (input from L7: shuffled)
    const int o = e - 114688;
    const int j = o & 7, lane = (o >> 3) & 63, ks = (o >> 9) & 3, T = o >> 11;
    const int k = klogf(ks * 32 + ((lane >> 4) << 3) + j);
    const int ch = T * 16 + (lane & 15);
    v = ptrs.p[21][k * 64 + ch];
    dst = 229376 + (((T * 4 + ks) * 64 + lane) << 4) + (j << 1);
  } else if (e < 126976) {                // C1 (input from C0: shuffled)
    const int o = e - 122880;
    const int j = o & 7, lane = (o >> 3) & 63, ks = (o >> 9) & 1, T = o >> 10;
    const int k = klogf(ks * 32 + ((lane >> 4) << 3) + j);
    const int ch = T * 16 + (lane & 15);
    v = ptrs.p[23][k * 64 + ch];
    dst = 245760 + (((T * 2 + ks) * 64 + lane) << 4) + (j << 1);
  } else {                                // C2 (input from C1: shuffled)
    const int o = e - 126976;
    const int j = o & 7, lane = (o >> 3) & 63, ks = (o >> 9) & 1, T = o >> 10;
    const int k = klogf(ks * 32 + ((lane >> 4) << 3) + j);
    const int ch = T * 16 + (lane & 15);
    v = ptrs.p[25][k * 64 + ch];
    dst = 253952 + (((T * 2 + ks) * 64 + lane) << 4) + (j << 1);
  }
  *(f16*)(ws + dst) = (f16)v;
}

// ---------------------------------------------------------------------------
// 4-fragment burst load (one och-tile worth at NKS=4; two at NKS=2)
// ---------------------------------------------------------------------------
__device__ __forceinline__ void loadF4(f16x8* A, const char* __restrict__ img,
                                       int fragBase, int lane) {
#pragma unroll
  for (int i = 0; i < 4; ++i)
    A[i] = *(const f16x8*)(img + (((fragBase + i) * 64 + lane) << 4));
}

// ---------------------------------------------------------------------------
// Chunk: acc-init + MFMAs for ct in [CTBASE, CTBASE+HCT), ptc = 4 point-tiles
// (64 pts/wave). A holds HCT*NKS fragments. INIT: 0 bias; 1 +pos*W5p; 2 +view
// ---------------------------------------------------------------------------
template<int HCT, int NKS, int INIT, int CTBASE>
__device__ __forceinline__ void qL(const f16x8 B[4][4], f32x4 acc[4][8],
                                   const f16x8* A,
                                   const float* __restrict__ P,
                                   const float px[4][3],
                                   const float* __restrict__ vw2,
                                   int biasOff, int kg, int wbase) {
#pragma unroll
  for (int ct = 0; ct < HCT; ++ct) {
    const int ochB = (CTBASE + ct) * 16 + kg * 4;
    const f32x4 bq = *(const f32x4*)(P + biasOff + ochB);
    f32x4 e0, e1, e2;
    if (INIT == 1) {
      e0 = *(const f32x4*)(P + 640 + ochB);
      e1 = *(const f32x4*)(P + 768 + ochB);
      e2 = *(const f32x4*)(P + 896 + ochB);
    } else if (INIT == 2) {
      e0 = *(const f32x4*)(P + 1856 + ochB);
      e1 = *(const f32x4*)(P + 1920 + ochB);
      e2 = *(const f32x4*)(P + 1984 + ochB);
    }
#pragma unroll
    for (int ptc = 0; ptc < 4; ++ptc) {
      f32x4 v = bq;
      if (INIT == 1)
        v += px[ptc][0] * e0 + px[ptc][1] * e1 + px[ptc][2] * e2;
      if (INIT == 2) {
        const int ray = (wbase + ptc * 16) >> 7;   // wave-uniform
        v += vw2[ray * 3] * e0 + vw2[ray * 3 + 1] * e1 + vw2[ray * 3 + 2] * e2;
      }
      acc[ptc][CTBASE + ct] = v;
    }
  }
  __builtin_amdgcn_s_setprio(1);
#pragma unroll
  for (int ct = 0; ct < HCT; ++ct)
#pragma unroll
    for (int ks = 0; ks < NKS; ++ks)
#pragma unroll
      for (int ptc = 0; ptc < 4; ++ptc)
        acc[ptc][CTBASE + ct] = __builtin_amdgcn_mfma_f32_16x16x32_f16(
            A[ct * NKS + ks], B[ptc][ks], acc[ptc][CTBASE + ct], 0, 0, 0);
  __builtin_amdgcn_s_setprio(0);
}

// relu + f16-convert acc -> next layer's B (own-lane identity via klog)
template<int NCT>
__device__ __forceinline__ void toB(const f32x4 acc[4][8], f16x8 B[4][4]) {
#pragma unroll
  for (int ptc = 0; ptc < 4; ++ptc)
#pragma unroll
    for (int ks = 0; ks < NCT / 2; ++ks) {
      f16x8 hb;
#pragma unroll
      for (int r = 0; r < 4; ++r) {
        hb[r]     = (f16)fmaxf(acc[ptc][2 * ks][r], 0.f);
        hb[4 + r] = (f16)fmaxf(acc[ptc][2 * ks + 1][r], 0.f);
      }
      B[ptc][ks] = hb;
    }
}

// ---------------------------------------------------------------------------
// Main: 512 threads, __launch_bounds__(512,2) — blessed thread config.
// 512 pts/block (grid 512), 8 waves x 64 pts (ptc=4), full 128-och/wave,
// zero act-LDS, one barrier. Chunk ping-pong Aa/Ab: load chunk(i+1) under
// MFMA chunk(i), crossing layer boundaries. acc 128 + B 64 + A 32 VGPRs.
// ---------------------------------------------------------------------------
__global__ __launch_bounds__(512, 2) void nerf_main(
    const float* __restrict__ pos, const float* __restrict__ view,
    const char* __restrict__ ws, float* __restrict__ out) {
  __shared__ __align__(16) float Lp[2560 + 1536 + 16];  // params | pos | view
  const int t = threadIdx.x, lane = t & 63, w = t >> 6;
  const int c = lane & 15, kg = lane >> 4;
  const int base = blockIdx.x * 512;   // 512 points per block
  const int wbase = w * 64;            // 64 points per wave
  const float* P = Lp;
  float* Lpos = Lp + 2560;
  float* Lvw = Lp + 4096;

  for (int i = t; i < 2560; i += 512) Lp[i] = ((const float*)(ws + WS_PARAMS))[i];
  for (int i = t; i < 1536; i += 512) Lpos[i] = pos[base * 3 + i];
  if (t < 12) Lvw[t] = view[(base >> 7) * 3 + t];
  __syncthreads();

  f16x8 Aa[4], Ab[4];
  loadF4(Aa, ws + 0, 0, lane);         // L1 chunk0 — in flight during L0

  // per-lane pos for its four point-tiles
  float px[4][3];
#pragma unroll
  for (int ptc = 0; ptc < 4; ++ptc) {
    const int lp = wbase + ptc * 16 + c;
#pragma unroll
    for (int d = 0; d < 3; ++d) px[ptc][d] = Lpos[lp * 3 + d];
  }

  // ---- L0: emit h0 directly as L1's B-frags (raw k-order) ----
  f16x8 B[4][4];
#pragma unroll
  for (int ptc = 0; ptc < 4; ++ptc)
#pragma unroll
    for (int ks = 0; ks < 4; ++ks) {
      f16x8 hb;
#pragma unroll
      for (int j = 0; j < 8; ++j) {
        const int ch = ks * 32 + kg * 8 + j;
        const float v = P[ch] + px[ptc][0] * P[128 + ch] + px[ptc][1] * P[256 + ch]
                      + px[ptc][2] * P[384 + ch];
        hb[j] = (f16)fmaxf(v, 0.f);
      }
      B[ptc][ks] = hb;
    }

  f32x4 acc[4][8];

  // chunk q computes ct=q from buf (q even: Aa, q odd: Ab) and preloads the
  // next chunk into the other buf; chunk 7 preloads the NEXT layer's chunk 0.
#define QCE(CTB, img_, fb, BIAS, INIT_)                                        \
  loadF4(Ab, img_, fb, lane);                                                  \
  qL<1, 4, INIT_, CTB>(B, acc, Aa, P, px, Lvw, BIAS, kg, wbase);
#define QCO(CTB, img_, fb, BIAS, INIT_)                                        \
  loadF4(Aa, img_, fb, lane);                                                  \
  qL<1, 4, INIT_, CTB>(B, acc, Ab, P, px, Lvw, BIAS, kg, wbase);
#define DLAYER(img_, imgNext, BIAS, INIT_)                                     \
  QCE(0, img_,  4, BIAS, INIT_) QCO(1, img_,  8, BIAS, INIT_)                  \
  QCE(2, img_, 12, BIAS, INIT_) QCO(3, img_, 16, BIAS, INIT_)                  \
  QCE(4, img_, 20, BIAS, INIT_) QCO(5, img_, 24, BIAS, INIT_)                  \
  QCE(6, img_, 28, BIAS, INIT_) QCO(7, imgNext, 0, BIAS, INIT_)

  DLAYER(ws +      0, ws +  32768, 1024, 0) toB<8>(acc, B);  // L1
  DLAYER(ws +  32768, ws +  65536, 1152, 0) toB<8>(acc, B);  // L2
  DLAYER(ws +  65536, ws +  98304, 1280, 0) toB<8>(acc, B);  // L3
  DLAYER(ws +  98304, ws + 131072, 1408, 0) toB<8>(acc, B);  // L4
  DLAYER(ws + 131072, ws + 163840,  512, 1) toB<8>(acc, B);  // L5 (skip)
  DLAYER(ws + 163840, ws + 196608, 1536, 0) toB<8>(acc, B);  // L6
  DLAYER(ws + 196608, ws + 229376, 1664, 0)                  // L7 (preloads C0)
#undef DLAYER
#undef QCE
#undef QCO

  // ---- sigma from L7 acc (f32, relu'd), in-register reduce ----
  float sig[4];
#pragma unroll
  for (int ptc = 0; ptc < 4; ++ptc) {
    float s = 0.f;
#pragma unroll
    for (int ct = 0; ct < 8; ++ct) {
      const f32x4 wq = *(const f32x4*)(P + 2176 + ct * 16 + kg * 4);
      const f32x4 a = acc[ptc][ct];
#pragma unroll
      for (int r = 0; r < 4; ++r) s += fmaxf(a[r], 0.f) * wq[r];
    }
    s += __shfl_xor(s, 16);
    s += __shfl_xor(s, 32);
    sig[ptc] = s + P[2304];
  }
  toB<8>(acc, B);                                            // h7 -> C0 B

  // ---- color chain. C0: NCT=4, NKS=4 (chunk0 already in Aa) ----
  loadF4(Ab, ws + 229376,  4, lane);
  qL<1, 4, 2, 0>(B, acc, Aa, P, px, Lvw, 1792, kg, wbase);
  loadF4(Aa, ws + 229376,  8, lane);
  qL<1, 4, 2, 1>(B, acc, Ab, P, px, Lvw, 1792, kg, wbase);
  loadF4(Ab, ws + 229376, 12, lane);
  qL<1, 4, 2, 2>(B, acc, Aa, P, px, Lvw, 1792, kg, wbase);
  loadF4(Aa, ws + 245760,  0, lane);                         // C1 ct0-1
  qL<1, 4, 2, 3>(B, acc, Ab, P, px, Lvw, 1792, kg, wbase);
  toB<4>(acc, B);                                            // C0 -> B (ks 0-1)

  // C1: NCT=4, NKS=2 (chunk = 2 ct)
  loadF4(Ab, ws + 245760, 4, lane);                          // C1 ct2-3
  qL<2, 2, 0, 0>(B, acc, Aa, P, px, Lvw, 2048, kg, wbase);
  loadF4(Aa, ws + 253952, 0, lane);                          // C2 ct0-1
  qL<2, 2, 0, 2>(B, acc, Ab, P, px, Lvw, 2048, kg, wbase);
  toB<4>(acc, B);                                            // C1 -> B

  // C2
  loadF4(Ab, ws + 253952, 4, lane);                          // C2 ct2-3
  qL<2, 2, 0, 0>(B, acc, Aa, P, px, Lvw, 2112, kg, wbase);
  qL<2, 2, 0, 2>(B, acc, Ab, P, px, Lvw, 2112, kg, wbase);

  // ---- rgb from C2 acc, in-register reduce; lanes kg==0 store float4 ----
#pragma unroll
  for (int ptc = 0; ptc < 4; ++ptc) {
    float a0 = 0.f, a1 = 0.f, a2 = 0.f;
#pragma unroll
    for (int ct = 0; ct < 4; ++ct) {
      const int ochB = ct * 16 + kg * 4;
      const f32x4 r0 = *(const f32x4*)(P + 2308 + ochB);
      const f32x4 r1 = *(const f32x4*)(P + 2372 + ochB);
      const f32x4 r2 = *(const f32x4*)(P + 2436 + ochB);
      const f32x4 a = acc[ptc][ct];
#pragma unroll
      for (int r = 0; r < 4; ++r) {
        const float h = fmaxf(a[r], 0.f);
        a0 += h * r0[r]; a1 += h * r1[r]; a2 += h * r2[r];
      }
    }
    a0 += __shfl_xor(a0, 16); a0 += __shfl_xor(a0, 32);
    a1 += __shfl_xor(a1, 16); a1 += __shfl_xor(a1, 32);
    a2 += __shfl_xor(a2, 16); a2 += __shfl_xor(a2, 32);
    if (kg == 0) {
      float4 o;
      o.x = a0 + P[2500]; o.y = a1 + P[2501]; o.z = a2 + P[2502]; o.w = sig[ptc];
      *(float4*)(out + (base + wbase + ptc * 16 + c) * 4) = o;
    }
  }
}

extern "C" void kernel_launch(void* const* d_in, const int* in_sizes, int n_in,
                              void* d_out, int out_size, void* d_ws, size_t ws_size,
                              hipStream_t stream) {
  Ptrs ptrs;
  for (int i = 0; i < 29; ++i) ptrs.p[i] = (const float*)d_in[i];
  char* ws = (char*)d_ws;
  nerf_prep<<<513, 256, 0, stream>>>(ptrs, ws);
  nerf_main<<<512, 512, 0, stream>>>((const float*)d_in[0], (const float*)d_in[2],
                                     ws, (float*)d_out);
}

// Round 15
// 77.879 us; speedup vs baseline: 1.4757x; 1.0572x over previous
//
#include <hip/hip_runtime.h>

typedef _Float16 f16;
typedef _Float16 f16x8 __attribute__((ext_vector_type(8)));
typedef float f32x4 __attribute__((ext_vector_type(4)));

// ---------------- d_ws layout ----------------
// [0, 262144) : f16 weight images, per-lane MFMA A-fragment order.
//   frag f = T*nks + ks at imgbase + (f*64 + lane)*16 + j*2, holding
//   W[k_logical][ch = T*16 + (lane&15)], k_raw = ks*32 + (lane>>4)*8 + j
//     k_logical = k_raw       for L1 (input from L0, raw order)
//     k_logical = klog(k_raw) for L2..L7, C0, C1, C2 (in-register chaining):
//     klog(q) = 32*(q>>5) + 16*((q>>2)&1) + 4*((q>>3)&3) + (q&3)
//   L1..L7 (128x128, nks=4): i*32768, i=0..6  (L5 uses dW5 rows 67+k)
//   C0h (128x64, nks=4): 229376 | C1 (64x64, nks=2): 245760 | C2: 253952
// [262144, +10240) : fp32 params block (same as R11..R14):
//   0 b0f[128] | 128 W0p[3][128] | 512 b5f[128] | 640 W5p[3][128]
//   1024 db1 1152 db2 1280 db3 1408 db4 1536 db6 1664 db7 (x128)
//   1792 cb0[64] | 1856 cWv[3][64] | 2048 cb1[64] | 2112 cb2[64]
//   2176 sW[128] | 2304 sb | 2308 rWT[3][64] | 2500 rb[3]
#define WS_PARAMS 262144

struct Ptrs { const float* p[29]; };

__device__ __forceinline__ int klogf(int q) {
  return ((q >> 5) << 5) | (((q >> 2) & 1) << 4) | (((q >> 3) & 3) << 2) | (q & 3);
}

// ---------------------------------------------------------------------------
// Prepass (verbatim from passing R11..R14)
// ---------------------------------------------------------------------------
__global__ void nerf_prep(Ptrs ptrs, char* __restrict__ ws) {
  const int t = threadIdx.x;
  if (blockIdx.x == 0) {
    float* P = (float*)(ws + WS_PARAMS);
    const float* cond = ptrs.p[1];
    const float* dW0 = ptrs.p[3];  const float* db0 = ptrs.p[4];
    const float* dW5 = ptrs.p[13]; const float* db5 = ptrs.p[14];
    if (t < 128) {
      float a0 = db0[t], a5 = db5[t];
      for (int k = 0; k < 64; ++k) {
        const float c = cond[k];
        a0 += c * dW0[(3 + k) * 128 + t];
        a5 += c * dW5[(3 + k) * 128 + t];
      }
      P[t] = a0;          // b0f
      P[512 + t] = a5;    // b5f
      for (int k = 0; k < 3; ++k) {
        P[128 + k * 128 + t] = dW0[k * 128 + t];   // W0p
        P[640 + k * 128 + t] = dW5[k * 128 + t];   // W5p
      }
      P[1024 + t] = ptrs.p[6][t];    // db1
      P[1152 + t] = ptrs.p[8][t];    // db2
      P[1280 + t] = ptrs.p[10][t];   // db3
      P[1408 + t] = ptrs.p[12][t];   // db4
      P[1536 + t] = ptrs.p[16][t];   // db6
      P[1664 + t] = ptrs.p[18][t];   // db7
      P[2176 + t] = ptrs.p[19][t];   // sW
    }
    if (t < 64) {
      P[1792 + t] = ptrs.p[22][t];   // cb0
      for (int k = 0; k < 3; ++k)    // cWv = cW0 rows 128..130
        P[1856 + k * 64 + t] = ptrs.p[21][(128 + k) * 64 + t];
      P[2048 + t] = ptrs.p[24][t];   // cb1
      P[2112 + t] = ptrs.p[26][t];   // cb2
      for (int c = 0; c < 3; ++c)    // rWT[3][64]
        P[2308 + c * 64 + t] = ptrs.p[27][t * 3 + c];
    }
    if (t == 0) {
      P[2304] = ptrs.p[20][0];                 // sb
      P[2500] = ptrs.p[28][0];
      P[2501] = ptrs.p[28][1];
      P[2502] = ptrs.p[28][2];                 // rb
    }
    if (t < 3)  P[2305 + t] = 0.f;
    if (t < 57) P[2503 + t] = 0.f;
    return;
  }
  // 131072 f16 weight-fragment elements across blocks 1..512
  const int e = (blockIdx.x - 1) * 256 + t;
  float v; int dst;
  if (e < 114688) {                       // L1..L7
    const int img = e >> 14, o = e & 16383;
    const int j = o & 7, lane = (o >> 3) & 63, ks = (o >> 9) & 3, T = o >> 11;
    const int kraw = ks * 32 + ((lane >> 4) << 3) + j;
    const int k = (img == 0) ? kraw : klogf(kraw);
    const int ch = T * 16 + (lane & 15);
    v = ptrs.p[5 + 2 * img][(k + (img == 4 ? 67 : 0)) * 128 + ch];
    dst = img * 32768 + (((T * 4 + ks) * 64 + lane) << 4) + (j << 1);
  } else if (e < 122880) {                // C0h (input from L7: shuffled)
    const int o = e - 114688;
    const int j = o & 7, lane = (o >> 3) & 63, ks = (o >> 9) & 3, T = o >> 11;
    const int k = klogf(ks * 32 + ((lane >> 4) << 3) + j);
    const int ch = T * 16 + (lane & 15);
    v = ptrs.p[21][k * 64 + ch];
    dst = 229376 + (((T * 4 + ks) * 64 + lane) << 4) + (j << 1);
  } else if (e < 126976) {                // C1 (input from C0: shuffled)
    const int o = e - 122880;
    const int j = o & 7, lane = (o >> 3) & 63, ks = (o >> 9) & 1, T = o >> 10;
    const int k = klogf(ks * 32 + ((lane >> 4) << 3) + j);
    const int ch = T * 16 + (lane & 15);
    v = ptrs.p[23][k * 64 + ch];
    dst = 245760 + (((T * 2 + ks) * 64 + lane) << 4) + (j << 1);
  } else {                                // C2 (input from C1: shuffled)
    const int o = e - 126976;
    const int j = o & 7, lane = (o >> 3) & 63, ks = (o >> 9) & 1, T = o >> 10;
    const int k = klogf(ks * 32 + ((lane >> 4) << 3) + j);
    const int ch = T * 16 + (lane & 15);
    v = ptrs.p[25][k * 64 + ch];
    dst = 253952 + (((T * 2 + ks) * 64 + lane) << 4) + (j << 1);
  }
  *(f16*)(ws + dst) = (f16)v;
}

// ---------------------------------------------------------------------------
// 4-fragment burst load (one och-tile worth at NKS=4; two at NKS=2)
// ---------------------------------------------------------------------------
__device__ __forceinline__ void loadF4(f16x8* A, const char* __restrict__ img,
                                       int fragBase, int lane) {
#pragma unroll
  for (int i = 0; i < 4; ++i)
    A[i] = *(const f16x8*)(img + (((fragBase + i) * 64 + lane) << 4));
}

// ---------------------------------------------------------------------------
// Chunk: MFMAs for ct in [CTBASE, CTBASE+HCT), ptc = 4 point-tiles.
// INIT==0: bias enters as the C operand of the first-ks MFMA (no acc-init
// VALU at all — bit-identical to seed-then-accumulate).
// INIT==1/2: explicit seed (bias + pos*W5p / + view*cWv), as before.
// ---------------------------------------------------------------------------
template<int HCT, int NKS, int INIT, int CTBASE>
__device__ __forceinline__ void qL(const f16x8 B[4][4], f32x4 acc[4][8],
                                   const f16x8* A,
                                   const float* __restrict__ P,
                                   const float px[4][3],
                                   const float* __restrict__ vw2,
                                   int biasOff, int kg, int wbase) {
#pragma unroll
  for (int ct = 0; ct < HCT; ++ct) {
    const int ochB = (CTBASE + ct) * 16 + kg * 4;
    const f32x4 bq = *(const f32x4*)(P + biasOff + ochB);
    if (INIT == 0) {
      __builtin_amdgcn_s_setprio(1);
#pragma unroll
      for (int ptc = 0; ptc < 4; ++ptc)
        acc[ptc][CTBASE + ct] = __builtin_amdgcn_mfma_f32_16x16x32_f16(
            A[ct * NKS + 0], B[ptc][0], bq, 0, 0, 0);
#pragma unroll
      for (int ks = 1; ks < NKS; ++ks)
#pragma unroll
        for (int ptc = 0; ptc < 4; ++ptc)
          acc[ptc][CTBASE + ct] = __builtin_amdgcn_mfma_f32_16x16x32_f16(
              A[ct * NKS + ks], B[ptc][ks], acc[ptc][CTBASE + ct], 0, 0, 0);
      __builtin_amdgcn_s_setprio(0);
    } else {
      f32x4 e0, e1, e2;
      if (INIT == 1) {
        e0 = *(const f32x4*)(P + 640 + ochB);
        e1 = *(const f32x4*)(P + 768 + ochB);
        e2 = *(const f32x4*)(P + 896 + ochB);
      } else {
        e0 = *(const f32x4*)(P + 1856 + ochB);
        e1 = *(const f32x4*)(P + 1920 + ochB);
        e2 = *(const f32x4*)(P + 1984 + ochB);
      }
#pragma unroll
      for (int ptc = 0; ptc < 4; ++ptc) {
        f32x4 v = bq;
        if (INIT == 1)
          v += px[ptc][0] * e0 + px[ptc][1] * e1 + px[ptc][2] * e2;
        if (INIT == 2) {
          const int ray = (wbase + ptc * 16) >> 7;   // wave-uniform
          v += vw2[ray * 3] * e0 + vw2[ray * 3 + 1] * e1 + vw2[ray * 3 + 2] * e2;
        }
        acc[ptc][CTBASE + ct] = v;
      }
      __builtin_amdgcn_s_setprio(1);
#pragma unroll
      for (int ks = 0; ks < NKS; ++ks)
#pragma unroll
        for (int ptc = 0; ptc < 4; ++ptc)
          acc[ptc][CTBASE + ct] = __builtin_amdgcn_mfma_f32_16x16x32_f16(
              A[ct * NKS + ks], B[ptc][ks], acc[ptc][CTBASE + ct], 0, 0, 0);
      __builtin_amdgcn_s_setprio(0);
    }
  }
}

// relu+convert acc -> next layer's B. Convert (RNE) first, relu in f16
// (bit-identical to f32-relu-then-convert; enables v_pk_max_f16).
template<int NCT>
__device__ __forceinline__ void toB(const f32x4 acc[4][8], f16x8 B[4][4]) {
#pragma unroll
  for (int ptc = 0; ptc < 4; ++ptc)
#pragma unroll
    for (int ks = 0; ks < NCT / 2; ++ks) {
      f16x8 hb;
#pragma unroll
      for (int r = 0; r < 4; ++r) {
        hb[r]     = (f16)acc[ptc][2 * ks][r];
        hb[4 + r] = (f16)acc[ptc][2 * ks + 1][r];
      }
#pragma unroll
      for (int e = 0; e < 8; ++e)
        hb[e] = hb[e] > (f16)0.f ? hb[e] : (f16)0.f;
      B[ptc][ks] = hb;
    }
}

// ---------------------------------------------------------------------------
// Main: 512 threads, __launch_bounds__(512,2), grid 512 — as passing R14.
// 512 pts/block, 8 waves x 64 pts (ptc=4), full 128-och/wave, zero act-LDS,
// one barrier. Chunk ping-pong Aa/Ab: load chunk(i+1) under MFMA chunk(i).
// ---------------------------------------------------------------------------
__global__ __launch_bounds__(512, 2) void nerf_main(
    const float* __restrict__ pos, const float* __restrict__ view,
    const char* __restrict__ ws, float* __restrict__ out) {
  __shared__ __align__(16) float Lp[2560 + 1536 + 16];  // params | pos | view
  const int t = threadIdx.x, lane = t & 63, w = t >> 6;
  const int c = lane & 15, kg = lane >> 4;
  const int base = blockIdx.x * 512;   // 512 points per block
  const int wbase = w * 64;            // 64 points per wave
  const float* P = Lp;
  float* Lpos = Lp + 2560;
  float* Lvw = Lp + 4096;

  for (int i = t; i < 2560; i += 512) Lp[i] = ((const float*)(ws + WS_PARAMS))[i];
  for (int i = t; i < 1536; i += 512) Lpos[i] = pos[base * 3 + i];
  if (t < 12) Lvw[t] = view[(base >> 7) * 3 + t];
  __syncthreads();

  f16x8 Aa[4], Ab[4];
  loadF4(Aa, ws + 0, 0, lane);         // L1 chunk0 — in flight during L0

  // per-lane pos for its four point-tiles
  float px[4][3];
#pragma unroll
  for (int ptc = 0; ptc < 4; ++ptc) {
    const int lp = wbase + ptc * 16 + c;
#pragma unroll
    for (int d = 0; d < 3; ++d) px[ptc][d] = Lpos[lp * 3 + d];
  }

  // ---- L0: emit h0 directly as L1's B-frags (raw k-order) ----
  f16x8 B[4][4];
#pragma unroll
  for (int ptc = 0; ptc < 4; ++ptc)
#pragma unroll
    for (int ks = 0; ks < 4; ++ks) {
      f16x8 hb;
#pragma unroll
      for (int j = 0; j < 8; ++j) {
        const int ch = ks * 32 + kg * 8 + j;
        const float v = P[ch] + px[ptc][0] * P[128 + ch] + px[ptc][1] * P[256 + ch]
                      + px[ptc][2] * P[384 + ch];
        hb[j] = (f16)fmaxf(v, 0.f);
      }
      B[ptc][ks] = hb;
    }

  f32x4 acc[4][8];

  // chunk q computes ct=q from buf (q even: Aa, q odd: Ab) and preloads the
  // next chunk into the other buf; chunk 7 preloads the NEXT layer's chunk 0.
#define QCE(CTB, img_, fb, BIAS, INIT_)                                        \
  loadF4(Ab, img_, fb, lane);                                                  \
  qL<1, 4, INIT_, CTB>(B, acc, Aa, P, px, Lvw, BIAS, kg, wbase);
#define QCO(CTB, img_, fb, BIAS, INIT_)                                        \
  loadF4(Aa, img_, fb, lane);                                                  \
  qL<1, 4, INIT_, CTB>(B, acc, Ab, P, px, Lvw, BIAS, kg, wbase);
#define DLAYER(img_, imgNext, BIAS, INIT_)                                     \
  QCE(0, img_,  4, BIAS, INIT_) QCO(1, img_,  8, BIAS, INIT_)                  \
  QCE(2, img_, 12, BIAS, INIT_) QCO(3, img_, 16, BIAS, INIT_)                  \
  QCE(4, img_, 20, BIAS, INIT_) QCO(5, img_, 24, BIAS, INIT_)                  \
  QCE(6, img_, 28, BIAS, INIT_) QCO(7, imgNext, 0, BIAS, INIT_)

  DLAYER(ws +      0, ws +  32768, 1024, 0) toB<8>(acc, B);  // L1
  DLAYER(ws +  32768, ws +  65536, 1152, 0) toB<8>(acc, B);  // L2
  DLAYER(ws +  65536, ws +  98304, 1280, 0) toB<8>(acc, B);  // L3
  DLAYER(ws +  98304, ws + 131072, 1408, 0) toB<8>(acc, B);  // L4
  DLAYER(ws + 131072, ws + 163840,  512, 1) toB<8>(acc, B);  // L5 (skip)
  DLAYER(ws + 163840, ws + 196608, 1536, 0) toB<8>(acc, B);  // L6
  DLAYER(ws + 196608, ws + 229376, 1664, 0)                  // L7 (preloads C0)
#undef DLAYER
#undef QCE
#undef QCO

  // ---- sigma from L7 acc (f32, relu'd), in-register reduce ----
  float sig[4];
#pragma unroll
  for (int ptc = 0; ptc < 4; ++ptc) {
    float s = 0.f;
#pragma unroll
    for (int ct = 0; ct < 8; ++ct) {
      const f32x4 wq = *(const f32x4*)(P + 2176 + ct * 16 + kg * 4);
      const f32x4 a = acc[ptc][ct];
#pragma unroll
      for (int r = 0; r < 4; ++r) s += fmaxf(a[r], 0.f) * wq[r];
    }
    s += __shfl_xor(s, 16);
    s += __shfl_xor(s, 32);
    sig[ptc] = s + P[2304];
  }
  toB<8>(acc, B);                                            // h7 -> C0 B

  // ---- color chain. C0: NCT=4, NKS=4 (chunk0 already in Aa) ----
  loadF4(Ab, ws + 229376,  4, lane);
  qL<1, 4, 2, 0>(B, acc, Aa, P, px, Lvw, 1792, kg, wbase);
  loadF4(Aa, ws + 229376,  8, lane);
  qL<1, 4, 2, 1>(B, acc, Ab, P, px, Lvw, 1792, kg, wbase);
  loadF4(Ab, ws + 229376, 12, lane);
  qL<1, 4, 2, 2>(B, acc, Aa, P, px, Lvw, 1792, kg, wbase);
  loadF4(Aa, ws + 245760,  0, lane);                         // C1 ct0-1
  qL<1, 4, 2, 3>(B, acc, Ab, P, px, Lvw, 1792, kg, wbase);
  toB<4>(acc, B);                                            // C0 -> B (ks 0-1)

  // C1: NCT=4, NKS=2 (chunk = 2 ct)
  loadF4(Ab, ws + 245760, 4, lane);                          // C1 ct2-3
  qL<2, 2, 0, 0>(B, acc, Aa, P, px, Lvw, 2048, kg, wbase);
  loadF4(Aa, ws + 253952, 0, lane);                          // C2 ct0-1
  qL<2, 2, 0, 2>(B, acc, Ab, P, px, Lvw, 2048, kg, wbase);
  toB<4>(acc, B);                                            // C1 -> B

  // C2
  loadF4(Ab, ws + 253952, 4, lane);                          // C2 ct2-3
  qL<2, 2, 0, 0>(B, acc, Aa, P, px, Lvw, 2112, kg, wbase);
  qL<2, 2, 0, 2>(B, acc, Ab, P, px, Lvw, 2112, kg, wbase);

  // ---- rgb from C2 acc, in-register reduce; lanes kg==0 store float4 ----
#pragma unroll
  for (int ptc = 0; ptc < 4; ++ptc) {
    float a0 = 0.f, a1 = 0.f, a2 = 0.f;
#pragma unroll
    for (int ct = 0; ct < 4; ++ct) {
      const int ochB = ct * 16 + kg * 4;
      const f32x4 r0 = *(const f32x4*)(P + 2308 + ochB);
      const f32x4 r1 = *(const f32x4*)(P + 2372 + ochB);
      const f32x4 r2 = *(const f32x4*)(P + 2436 + ochB);
      const f32x4 a = acc[ptc][ct];
#pragma unroll
      for (int r = 0; r < 4; ++r) {
        const float h = fmaxf(a[r], 0.f);
        a0 += h * r0[r]; a1 += h * r1[r]; a2 += h * r2[r];
      }
    }
    a0 += __shfl_xor(a0, 16); a0 += __shfl_xor(a0, 32);
    a1 += __shfl_xor(a1, 16); a1 += __shfl_xor(a1, 32);
    a2 += __shfl_xor(a2, 16); a2 += __shfl_xor(a2, 32);
    if (kg == 0) {
      float4 o;
      o.x = a0 + P[2500]; o.y = a1 + P[2501]; o.z = a2 + P[2502]; o.w = sig[ptc];
      *(float4*)(out + (base + wbase + ptc * 16 + c) * 4) = o;
    }
  }
}

extern "C" void kernel_launch(void* const* d_in, const int* in_sizes, int n_in,
                              void* d_out, int out_size, void* d_ws, size_t ws_size,
                              hipStream_t stream) {
  Ptrs ptrs;
  for (int i = 0; i < 29; ++i) ptrs.p[i] = (const float*)d_in[i];
  char* ws = (char*)d_ws;
  nerf_prep<<<513, 256, 0, stream>>>(ptrs, ws);
  nerf_main<<<512, 512, 0, stream>>>((const float*)d_in[0], (const float*)d_in[2],
                                     ws, (float*)d_out);
}